// Round 4
// baseline (73599.957 us; speedup 1.0000x reference)
//
#include <hip/hip_runtime.h>
#include <math.h>

// ---------------------------------------------------------------------------
// LSTM_FEAT_2: T=4096 strictly-sequential 2-layer LSTM with log-softmax
// feedback. Persistent kernel, weights register-resident, 3 global
// barriers/step via agent-scope (LLC) atomics.
//
// Math folding:
//   feat_t = Ws@x_t + bs                       (startup GEMM -> ws)
//   embed feedback: W_ih1e@embed = WC@y - rsWC*lse + W_ih1e@bm,
//     WC = W_ih1e@Wm  (startup GEMM), lse = logsumexp(y)
//   gates1 = W_ih1s@feat + W_hh1@h1 + WC@y_prev + biasA [+ bE - rsWC*lse]
//   gates2 = W_ih2@h1 + W_hh2@h2 + biasB
//   y      = Wl@h2 + bl ;  out[t] = y - lse  (== log_softmax(y))
//
// R4 change: __attribute__((amdgpu_waves_per_eu(2,2))).
// Evidence trail: R2/R3 kept VGPR_Count=116 and WRITE_SIZE=EXACTLY 200 MiB
// (=1600B/thread x 131072 threads) -> the pinned weights were spilled to
// scratch and re-read from LLC every step (66MB/step ~ 3.8TB/s = the
// measured 17.2us/step). launch_bounds' 2nd arg only sets a MINIMUM
// waves/EU; the allocator still TARGETED 4 waves/EU (128-VGPR cap -> 116).
// amdgpu_waves_per_eu(2,2) caps the target at 2 waves/EU = 256-VGPR budget,
// which fits the ~200-reg pressure, so the pinned weights can stay live.
// ---------------------------------------------------------------------------

#define T_STEPS 4096
#define NWG 256

// ws layout (bytes)
#define WS_CTR   0                 // 12288 u32 barrier counters (48 KiB)
#define WS_H1    49152             // float h1buf[2][1024]
#define WS_H2    57344             // float h2buf[2][1024]
#define WS_Y     65536             // float ybuf[2][512]
#define WS_ZERO_BYTES 69632        // memset range: ctrs + state
#define WS_BIASA 69632             // float[4096] = b_ih1+b_hh1
#define WS_BIASB 86016             // float[4096] = b_ih2+b_hh2
#define WS_BIASE 102400            // float[4096] = W_ih1e@bm
#define WS_RSWC  118784            // float[4096] = rowsum(WC)
#define WS_FEAT  135168            // float[4096][512]
#define WS_WC    8523776           // float[4096][512]
// total ~16.2 MB

// Opaque register pin: forces the value to live in a VGPR and prevents
// rematerialization/sinking of the originating load into the loop.
#define PIN4(v) asm volatile("" : "+v"((v).x), "+v"((v).y), "+v"((v).z), "+v"((v).w))
#define PIN1(v) asm volatile("" : "+v"(v))

__device__ __forceinline__ float AL(const float* p){
  return __hip_atomic_load(p, __ATOMIC_RELAXED, __HIP_MEMORY_SCOPE_AGENT);
}
__device__ __forceinline__ void AS(float* p, float v){
  __hip_atomic_store(p, v, __ATOMIC_RELAXED, __HIP_MEMORY_SCOPE_AGENT);
}
__device__ __forceinline__ float sigm(float x){ return 1.0f/(1.0f+expf(-x)); }

__device__ __forceinline__ void gbarrier(unsigned* ctrs, int b){
  __syncthreads();
  if (threadIdx.x == 0){
    // ensure our agent-scope data stores have reached the coherence point
    asm volatile("s_waitcnt vmcnt(0) lgkmcnt(0)" ::: "memory");
    __hip_atomic_fetch_add(&ctrs[b], 1u, __ATOMIC_RELAXED, __HIP_MEMORY_SCOPE_AGENT);
    while (__hip_atomic_load(&ctrs[b], __ATOMIC_RELAXED, __HIP_MEMORY_SCOPE_AGENT) < (unsigned)NWG) {}
  }
  __syncthreads();
}

// ---------------------------------------------------------------------------
// startup kernel: feat[t][k] = sum_d Ws[k][d]*x[t][d] + bs[k]
// grid 256, block 512; wg handles 16 t-rows
__global__ __launch_bounds__(512) void feat_kernel(
    const float* __restrict__ x, const float* __restrict__ Ws,
    const float* __restrict__ bs, float* __restrict__ feat)
{
  __shared__ float s_x[16][360];
  __shared__ float s_w[512][20];
  const int bid = blockIdx.x, tid = threadIdx.x;
  const int t0 = bid * 16;
  for (int tt = 0; tt < 16; tt++)
    if (tid < 360) s_x[tt][tid] = x[(t0+tt)*360 + tid];
  float acc[16];
  #pragma unroll
  for (int i = 0; i < 16; i++) acc[i] = 0.f;
  for (int d0 = 0; d0 < 360; d0 += 16){
    const int dn = (360 - d0 < 16) ? (360 - d0) : 16;
    __syncthreads();
    if (dn == 16){
      #pragma unroll
      for (int c4 = 0; c4 < 4; c4++)
        *(float4*)&s_w[tid][c4*4] = *(const float4*)&Ws[tid*360 + d0 + c4*4];
    } else {
      for (int c = 0; c < dn; c++) s_w[tid][c] = Ws[tid*360 + d0 + c];
    }
    __syncthreads();
    for (int c = 0; c < dn; c++){
      float wv = s_w[tid][c];
      #pragma unroll
      for (int tt = 0; tt < 16; tt++) acc[tt] += wv * s_x[tt][d0 + c];
    }
  }
  for (int tt = 0; tt < 16; tt++)
    feat[(t0+tt)*512 + tid] = acc[tt] + bs[tid];
}

// ---------------------------------------------------------------------------
// startup kernel: WC[r][m] = sum_e W_ih1[r][512+e] * Wm[e][m]
// grid 256, block 512; wg handles 16 r-rows
__global__ __launch_bounds__(512) void wc_kernel(
    const float* __restrict__ Wih1, const float* __restrict__ Wm,
    float* __restrict__ WCo)
{
  __shared__ float s_a[16][128];
  const int bid = blockIdx.x, tid = threadIdx.x;
  const int r0 = bid * 16;
  for (int idx = tid; idx < 2048; idx += 512){
    int rr = idx >> 7, e = idx & 127;
    s_a[rr][e] = Wih1[(r0+rr)*640 + 512 + e];
  }
  __syncthreads();
  float acc[16];
  #pragma unroll
  for (int i = 0; i < 16; i++) acc[i] = 0.f;
  for (int e = 0; e < 128; e++){
    float wv = Wm[e*512 + tid];
    #pragma unroll
    for (int rr = 0; rr < 16; rr++) acc[rr] += s_a[rr][e] * wv;
  }
  for (int rr = 0; rr < 16; rr++) WCo[(r0+rr)*512 + tid] = acc[rr];
}

// ---------------------------------------------------------------------------
// startup kernel: bias folds + rowsum(WC)
__global__ void bias_kernel(
    const float* __restrict__ bih1, const float* __restrict__ bhh1,
    const float* __restrict__ bih2, const float* __restrict__ bhh2,
    const float* __restrict__ Wih1, const float* __restrict__ bm,
    const float* __restrict__ WCo,
    float* __restrict__ biasA, float* __restrict__ biasB,
    float* __restrict__ biasE, float* __restrict__ rsWC)
{
  const int r = blockIdx.x * 256 + threadIdx.x;
  if (r >= 4096) return;
  biasA[r] = bih1[r] + bhh1[r];
  biasB[r] = bih2[r] + bhh2[r];
  float be = 0.f;
  for (int e = 0; e < 128; e++) be += Wih1[r*640 + 512 + e] * bm[e];
  biasE[r] = be;
  float rs = 0.f;
  for (int m = 0; m < 512; m++) rs += WCo[r*512 + m];
  rsWC[r] = rs;
}

// ---------------------------------------------------------------------------
// persistent sequential kernel. 256 wgs x 512 threads, 1 wg/CU.
// Thread map: wave w=tid>>6, lane l=tid&63, out o=l>>2 (16 gate-rows/wg),
// part p=w*4+(l&3) (32 x 64-wide dot slices).
__global__ __launch_bounds__(512)
__attribute__((amdgpu_waves_per_eu(2, 2)))
void lstm_persist(
    const float* __restrict__ Wih1, const float* __restrict__ Whh1,
    const float* __restrict__ Wih2, const float* __restrict__ Whh2,
    const float* __restrict__ Wl,   const float* __restrict__ blp,
    char* __restrict__ wsb, float* __restrict__ out)
{
  unsigned* ctrs = (unsigned*)(wsb + WS_CTR);
  float* h1b = (float*)(wsb + WS_H1);
  float* h2b = (float*)(wsb + WS_H2);
  float* yb  = (float*)(wsb + WS_Y);
  const float* biasA_ = (const float*)(wsb + WS_BIASA);
  const float* biasB_ = (const float*)(wsb + WS_BIASB);
  const float* biasE_ = (const float*)(wsb + WS_BIASE);
  const float* rsWC_  = (const float*)(wsb + WS_RSWC);
  const float* feat   = (const float*)(wsb + WS_FEAT);
  const float* WCp    = (const float*)(wsb + WS_WC);

  const int wid = blockIdx.x, tid = threadIdx.x;
  const int w = tid >> 6, l = tid & 63;
  const int o = l >> 2, p4 = l & 3, p = w*4 + p4;
  const int rA = (o >> 2)*1024 + wid*4 + (o & 3);   // gate row (shared by L1/L2)

  // ---- load register-resident weight slices (once), then PIN them ----
  float4 wA[16], wB[16], wC;
  #pragma unroll
  for (int i = 0; i < 16; i++){
    int q = p*64 + i*4;
    const float* src;
    if (q < 512)        src = &Wih1[rA*640 + q];
    else if (q < 1536)  src = &Whh1[rA*1024 + (q - 512)];
    else                src = &WCp [rA*512  + (q - 1536)];
    wA[i] = *(const float4*)src;
  }
  #pragma unroll
  for (int i = 0; i < 16; i++){
    int q = p*64 + i*4;
    wB[i] = (q < 1024) ? *(const float4*)&Wih2[rA*1024 + q]
                       : *(const float4*)&Whh2[rA*1024 + (q - 1024)];
  }
  {
    int P = w*32 + (l & 31), o2 = l >> 5;
    wC = *(const float4*)&Wl[(wid*2 + o2)*1024 + P*4];
  }
  float biasAreg = 0.f, biasBreg = 0.f, bEreg = 0.f, rsReg = 0.f, blReg = 0.f;
  float c1 = 0.f, c2 = 0.f;
  if (w == 0 && l < 16){
    int r = (l >> 2)*1024 + wid*4 + (l & 3);
    biasAreg = biasA_[r]; biasBreg = biasB_[r];
    bEreg = biasE_[r];    rsReg = rsWC_[r];
  }
  if (w == 0 && l < 2) blReg = blp[wid*2 + l];

  // Force all loop-invariant weights to be VGPR-resident across the loop.
  #pragma unroll
  for (int i = 0; i < 16; i++){ PIN4(wA[i]); }
  #pragma unroll
  for (int i = 0; i < 16; i++){ PIN4(wB[i]); }
  PIN4(wC);
  PIN1(biasAreg); PIN1(biasBreg); PIN1(bEreg); PIN1(rsReg); PIN1(blReg);

  __shared__ float s_in[32*68];     // padded (+4) 64-wide slices: bank-safe
  __shared__ float s_part[16*8];

  for (int t = 0; t < T_STEPS; t++){
    const int rb = t & 1, wbuf = (t + 1) & 1;

    // ================= Phase A: gates1 -> h1 =================
    {
      int q0 = tid*4; float4 v;
      if (q0 < 512){
        v = *(const float4*)&feat[t*512 + q0];
      } else if (q0 < 1536){
        int qq = rb*1024 + (q0 - 512);
        v.x = AL(&h1b[qq]); v.y = AL(&h1b[qq+1]); v.z = AL(&h1b[qq+2]); v.w = AL(&h1b[qq+3]);
      } else {
        int qq = rb*512 + (q0 - 1536);
        v.x = AL(&yb[qq]); v.y = AL(&yb[qq+1]); v.z = AL(&yb[qq+2]); v.w = AL(&yb[qq+3]);
      }
      *(float4*)&s_in[(q0 >> 6)*68 + (q0 & 63)] = v;
    }
    __syncthreads();

    float lse = 0.f;
    if (w == 0 && t > 0){
      // redundant per-wg logsumexp over the 512 y values (slices 24..31)
      int sl2 = 24 + (l >> 3), wd2 = (l & 7)*8;
      float4 a  = *(float4*)&s_in[sl2*68 + wd2];
      float4 bq = *(float4*)&s_in[sl2*68 + wd2 + 4];
      float m0 = fmaxf(fmaxf(fmaxf(a.x,a.y), fmaxf(a.z,a.w)),
                       fmaxf(fmaxf(bq.x,bq.y), fmaxf(bq.z,bq.w)));
      for (int mk = 32; mk; mk >>= 1) m0 = fmaxf(m0, __shfl_xor(m0, mk));
      float s = expf(a.x-m0)+expf(a.y-m0)+expf(a.z-m0)+expf(a.w-m0)
              + expf(bq.x-m0)+expf(bq.y-m0)+expf(bq.z-m0)+expf(bq.w-m0);
      for (int mk = 32; mk; mk >>= 1) s += __shfl_xor(s, mk);
      lse = m0 + logf(s);
      if (wid == 0){  // wg0 emits output row t-1 = y - lse
        float4 o1 = make_float4(a.x-lse, a.y-lse, a.z-lse, a.w-lse);
        float4 o2 = make_float4(bq.x-lse, bq.y-lse, bq.z-lse, bq.w-lse);
        *(float4*)&out[(t-1)*512 + l*8]     = o1;
        *(float4*)&out[(t-1)*512 + l*8 + 4] = o2;
      }
    }

    float acc = 0.f;
    #pragma unroll
    for (int i = 0; i < 16; i++){
      float4 xv = *(float4*)&s_in[p*68 + i*4];
      acc += wA[i].x*xv.x; acc += wA[i].y*xv.y;
      acc += wA[i].z*xv.z; acc += wA[i].w*xv.w;
    }
    acc += __shfl_xor(acc, 1); acc += __shfl_xor(acc, 2);
    if (p4 == 0) s_part[o*8 + w] = acc;
    __syncthreads();
    if (w == 0 && l < 16){
      float4 pa = *(float4*)&s_part[l*8];
      float4 pb = *(float4*)&s_part[l*8 + 4];
      float sum = pa.x+pa.y+pa.z+pa.w + pb.x+pb.y+pb.z+pb.w + biasAreg;
      if (t > 0) sum += bEreg - rsReg*lse;
      float gi = __shfl(sum, (l & 3));
      float gf = __shfl(sum, 4 + (l & 3));
      float gg = __shfl(sum, 8 + (l & 3));
      float go = __shfl(sum, 12 + (l & 3));
      if (l < 4){
        float cn = sigm(gf)*c1 + sigm(gi)*tanhf(gg);
        c1 = cn;
        float hn = sigm(go)*tanhf(cn);
        AS(&h1b[wbuf*1024 + wid*4 + l], hn);
      }
    }
    gbarrier(ctrs, t*3 + 0);

    // ================= Phase B: gates2 -> h2 =================
    {
      int q0 = tid*4; float4 v;
      float* src = (q0 < 1024) ? h1b : h2b;
      int qq = (q0 < 1024) ? (wbuf*1024 + q0) : (rb*1024 + (q0 - 1024));
      v.x = AL(&src[qq]); v.y = AL(&src[qq+1]); v.z = AL(&src[qq+2]); v.w = AL(&src[qq+3]);
      *(float4*)&s_in[(q0 >> 6)*68 + (q0 & 63)] = v;
    }
    __syncthreads();
    acc = 0.f;
    #pragma unroll
    for (int i = 0; i < 16; i++){
      float4 xv = *(float4*)&s_in[p*68 + i*4];
      acc += wB[i].x*xv.x; acc += wB[i].y*xv.y;
      acc += wB[i].z*xv.z; acc += wB[i].w*xv.w;
    }
    acc += __shfl_xor(acc, 1); acc += __shfl_xor(acc, 2);
    if (p4 == 0) s_part[o*8 + w] = acc;
    __syncthreads();
    if (w == 0 && l < 16){
      float4 pa = *(float4*)&s_part[l*8];
      float4 pb = *(float4*)&s_part[l*8 + 4];
      float sum = pa.x+pa.y+pa.z+pa.w + pb.x+pb.y+pb.z+pb.w + biasBreg;
      float gi = __shfl(sum, (l & 3));
      float gf = __shfl(sum, 4 + (l & 3));
      float gg = __shfl(sum, 8 + (l & 3));
      float go = __shfl(sum, 12 + (l & 3));
      if (l < 4){
        float cn = sigm(gf)*c2 + sigm(gi)*tanhf(gg);
        c2 = cn;
        float hn = sigm(go)*tanhf(cn);
        AS(&h2b[wbuf*1024 + wid*4 + l], hn);
      }
    }
    gbarrier(ctrs, t*3 + 1);

    // ================= Phase C: y = Wl@h2 + bl =================
    if (tid < 256){
      int q0 = tid*4; float4 v;
      int qq = wbuf*1024 + q0;
      v.x = AL(&h2b[qq]); v.y = AL(&h2b[qq+1]); v.z = AL(&h2b[qq+2]); v.w = AL(&h2b[qq+3]);
      *(float4*)&s_in[q0] = v;   // flat layout for phase C
    }
    __syncthreads();
    {
      int P = w*32 + (l & 31), o2 = l >> 5;
      float4 xv = *(float4*)&s_in[P*4];
      float a2 = wC.x*xv.x + wC.y*xv.y + wC.z*xv.z + wC.w*xv.w;
      for (int mk = 16; mk; mk >>= 1) a2 += __shfl_xor(a2, mk);
      if ((l & 31) == 0) s_part[o2*8 + w] = a2;
    }
    __syncthreads();
    if (w == 0 && l < 2){
      float4 pa = *(float4*)&s_part[l*8];
      float4 pb = *(float4*)&s_part[l*8 + 4];
      float yv = pa.x+pa.y+pa.z+pa.w + pb.x+pb.y+pb.z+pb.w + blReg;
      AS(&yb[wbuf*512 + wid*2 + l], yv);
    }
    gbarrier(ctrs, t*3 + 2);
  }

  // ---- tail: emit output row T-1 (final y buffer index = (T)&1 = 0) ----
  if (wid == 0 && w == 0){
    int idx = l*8;
    float yv[8];
    #pragma unroll
    for (int i = 0; i < 8; i++) yv[i] = AL(&yb[idx + i]);
    float m0 = yv[0];
    #pragma unroll
    for (int i = 1; i < 8; i++) m0 = fmaxf(m0, yv[i]);
    for (int mk = 32; mk; mk >>= 1) m0 = fmaxf(m0, __shfl_xor(m0, mk));
    float s = 0.f;
    #pragma unroll
    for (int i = 0; i < 8; i++) s += expf(yv[i] - m0);
    for (int mk = 32; mk; mk >>= 1) s += __shfl_xor(s, mk);
    float lse = m0 + logf(s);
    #pragma unroll
    for (int i = 0; i < 8; i++) out[(T_STEPS-1)*512 + idx + i] = yv[i] - lse;
  }
}

// ---------------------------------------------------------------------------
extern "C" void kernel_launch(void* const* d_in, const int* in_sizes, int n_in,
                              void* d_out, int out_size, void* d_ws, size_t ws_size,
                              hipStream_t stream)
{
  const float* x    = (const float*)d_in[0];
  const float* Ws   = (const float*)d_in[1];
  const float* bs   = (const float*)d_in[2];
  const float* Wih1 = (const float*)d_in[3];
  const float* Whh1 = (const float*)d_in[4];
  const float* bih1 = (const float*)d_in[5];
  const float* bhh1 = (const float*)d_in[6];
  const float* Wih2 = (const float*)d_in[7];
  const float* Whh2 = (const float*)d_in[8];
  const float* bih2 = (const float*)d_in[9];
  const float* bhh2 = (const float*)d_in[10];
  const float* Wl   = (const float*)d_in[11];
  const float* bl   = (const float*)d_in[12];
  const float* Wm   = (const float*)d_in[13];
  const float* bm   = (const float*)d_in[14];
  char* wsb  = (char*)d_ws;
  float* out = (float*)d_out;

  // zero barrier counters + recurrent state (fresh every call / graph replay)
  hipMemsetAsync(wsb, 0, WS_ZERO_BYTES, stream);

  feat_kernel<<<256, 512, 0, stream>>>(x, Ws, bs, (float*)(wsb + WS_FEAT));
  wc_kernel  <<<256, 512, 0, stream>>>(Wih1, Wm, (float*)(wsb + WS_WC));
  bias_kernel<<<16, 256, 0, stream>>>(bih1, bhh1, bih2, bhh2, Wih1, bm,
                                      (const float*)(wsb + WS_WC),
                                      (float*)(wsb + WS_BIASA), (float*)(wsb + WS_BIASB),
                                      (float*)(wsb + WS_BIASE), (float*)(wsb + WS_RSWC));
  lstm_persist<<<256, 512, 0, stream>>>(Wih1, Whh1, Wih2, Whh2, Wl, bl, wsb, out);
}

// Round 5
// 39823.505 us; speedup vs baseline: 1.8482x; 1.8482x over previous
//
#include <hip/hip_runtime.h>
#include <math.h>

// ---------------------------------------------------------------------------
// LSTM_FEAT_2: T=4096 strictly-sequential 2-layer LSTM with log-softmax
// feedback. Persistent kernel, 3 global barriers/step.
//
// R5 redesign (two independent levers, disambiguated by counters):
//  1) BLOCK=1024 (16 waves): per-thread weight share drops 132 -> 66 floats,
//     fitting under the 128-VGPR cap the backend enforced in R1-R4 (VGPR=116,
//     WRITE_SIZE=exactly 200MiB scratch every round). No allocator fights.
//  2) Hierarchical barrier: 8 group ctrs (32 RMWs each, separate LLC pages)
//     -> root (8 RMWs) -> 1 flag store; wgs poll read-only flag w/ s_sleep.
//     Replaces 256-way contended RMW+poll on a single counter.
//
// Math folding (unchanged):
//   feat_t = Ws@x_t + bs                       (startup GEMM -> ws)
//   W_ih1e@embed = WC@y - rsWC*lse + W_ih1e@bm,  WC = W_ih1e@Wm
//   gates1 = W_ih1s@feat + W_hh1@h1 + WC@y_prev + biasA [+ bE - rsWC*lse]
//   gates2 = W_ih2@h1 + W_hh2@h2 + biasB
//   y      = Wl@h2 + bl ;  out[t] = y - lse
// ---------------------------------------------------------------------------

#define T_STEPS 4096
#define NWG 256
#define NBAR (T_STEPS*3)

// ws layout (bytes)
#define WS_BAR   0                 // 10 pages x 48KB: l1[8], root, flag
#define BAR_PAGE 49152             // NBAR * 4
#define WS_H1    491520            // float h1buf[2][1024]
#define WS_H2    499712            // float h2buf[2][1024]
#define WS_Y     507904            // float ybuf[2][512]
#define WS_ZERO_BYTES 512000
#define WS_BIASA 512000            // float[4096] = b_ih1+b_hh1
#define WS_BIASB 528384            // float[4096] = b_ih2+b_hh2
#define WS_BIASE 544768            // float[4096] = W_ih1e@bm
#define WS_RSWC  561152            // float[4096] = rowsum(WC)
#define WS_FEAT  577536            // float[4096][512]
#define WS_WC    8966144           // float[4096][512]
// total ~16.6 MB

#define PIN4(v) asm volatile("" : "+v"((v).x), "+v"((v).y), "+v"((v).z), "+v"((v).w))
#define PIN2(v) asm volatile("" : "+v"((v).x), "+v"((v).y))
#define PIN1(v) asm volatile("" : "+v"(v))

__device__ __forceinline__ float AL(const float* p){
  return __hip_atomic_load(p, __ATOMIC_RELAXED, __HIP_MEMORY_SCOPE_AGENT);
}
__device__ __forceinline__ float2 AL2(const float* p){
  unsigned long long u = __hip_atomic_load((const unsigned long long*)p,
                                           __ATOMIC_RELAXED, __HIP_MEMORY_SCOPE_AGENT);
  union { unsigned long long u; float2 f; } c; c.u = u; return c.f;
}
__device__ __forceinline__ void AS(float* p, float v){
  __hip_atomic_store(p, v, __ATOMIC_RELAXED, __HIP_MEMORY_SCOPE_AGENT);
}
__device__ __forceinline__ float sigm(float x){ return 1.0f/(1.0f+expf(-x)); }

// hierarchical 256-wg barrier: l1 (32 arrivals x 8 groups) -> root (8) -> flag
__device__ __forceinline__ void gbarrier(char* wsb, int wid, int b){
  __syncthreads();
  if (threadIdx.x == 0){
    asm volatile("s_waitcnt vmcnt(0) lgkmcnt(0)" ::: "memory");
    unsigned* l1   = (unsigned*)(wsb) + (unsigned)(wid >> 5) * (BAR_PAGE/4) + b;
    unsigned* flag = (unsigned*)(wsb + 9*BAR_PAGE) + b;
    unsigned r = __hip_atomic_fetch_add(l1, 1u, __ATOMIC_RELAXED, __HIP_MEMORY_SCOPE_AGENT);
    if (r == 31u){
      unsigned* root = (unsigned*)(wsb + 8*BAR_PAGE) + b;
      unsigned rr = __hip_atomic_fetch_add(root, 1u, __ATOMIC_RELAXED, __HIP_MEMORY_SCOPE_AGENT);
      if (rr == 7u)
        __hip_atomic_store(flag, 1u, __ATOMIC_RELAXED, __HIP_MEMORY_SCOPE_AGENT);
    }
    while (__hip_atomic_load(flag, __ATOMIC_RELAXED, __HIP_MEMORY_SCOPE_AGENT) == 0u){
      __builtin_amdgcn_s_sleep(1);
    }
    asm volatile("" ::: "memory");
  }
  __syncthreads();
}

// ---------------------------------------------------------------------------
// startup kernel: feat[t][k] = sum_d Ws[k][d]*x[t][d] + bs[k]
__global__ __launch_bounds__(512) void feat_kernel(
    const float* __restrict__ x, const float* __restrict__ Ws,
    const float* __restrict__ bs, float* __restrict__ feat)
{
  __shared__ float s_x[16][360];
  __shared__ float s_w[512][20];
  const int bid = blockIdx.x, tid = threadIdx.x;
  const int t0 = bid * 16;
  for (int tt = 0; tt < 16; tt++)
    if (tid < 360) s_x[tt][tid] = x[(t0+tt)*360 + tid];
  float acc[16];
  #pragma unroll
  for (int i = 0; i < 16; i++) acc[i] = 0.f;
  for (int d0 = 0; d0 < 360; d0 += 16){
    const int dn = (360 - d0 < 16) ? (360 - d0) : 16;
    __syncthreads();
    if (dn == 16){
      #pragma unroll
      for (int c4 = 0; c4 < 4; c4++)
        *(float4*)&s_w[tid][c4*4] = *(const float4*)&Ws[tid*360 + d0 + c4*4];
    } else {
      for (int c = 0; c < dn; c++) s_w[tid][c] = Ws[tid*360 + d0 + c];
    }
    __syncthreads();
    for (int c = 0; c < dn; c++){
      float wv = s_w[tid][c];
      #pragma unroll
      for (int tt = 0; tt < 16; tt++) acc[tt] += wv * s_x[tt][d0 + c];
    }
  }
  for (int tt = 0; tt < 16; tt++)
    feat[(t0+tt)*512 + tid] = acc[tt] + bs[tid];
}

// ---------------------------------------------------------------------------
// startup kernel: WC[r][m] = sum_e W_ih1[r][512+e] * Wm[e][m]
__global__ __launch_bounds__(512) void wc_kernel(
    const float* __restrict__ Wih1, const float* __restrict__ Wm,
    float* __restrict__ WCo)
{
  __shared__ float s_a[16][128];
  const int bid = blockIdx.x, tid = threadIdx.x;
  const int r0 = bid * 16;
  for (int idx = tid; idx < 2048; idx += 512){
    int rr = idx >> 7, e = idx & 127;
    s_a[rr][e] = Wih1[(r0+rr)*640 + 512 + e];
  }
  __syncthreads();
  float acc[16];
  #pragma unroll
  for (int i = 0; i < 16; i++) acc[i] = 0.f;
  for (int e = 0; e < 128; e++){
    float wv = Wm[e*512 + tid];
    #pragma unroll
    for (int rr = 0; rr < 16; rr++) acc[rr] += s_a[rr][e] * wv;
  }
  for (int rr = 0; rr < 16; rr++) WCo[(r0+rr)*512 + tid] = acc[rr];
}

// ---------------------------------------------------------------------------
// startup kernel: bias folds + rowsum(WC)
__global__ void bias_kernel(
    const float* __restrict__ bih1, const float* __restrict__ bhh1,
    const float* __restrict__ bih2, const float* __restrict__ bhh2,
    const float* __restrict__ Wih1, const float* __restrict__ bm,
    const float* __restrict__ WCo,
    float* __restrict__ biasA, float* __restrict__ biasB,
    float* __restrict__ biasE, float* __restrict__ rsWC)
{
  const int r = blockIdx.x * 256 + threadIdx.x;
  if (r >= 4096) return;
  biasA[r] = bih1[r] + bhh1[r];
  biasB[r] = bih2[r] + bhh2[r];
  float be = 0.f;
  for (int e = 0; e < 128; e++) be += Wih1[r*640 + 512 + e] * bm[e];
  biasE[r] = be;
  float rs = 0.f;
  for (int m = 0; m < 512; m++) rs += WCo[r*512 + m];
  rsWC[r] = rs;
}

// ---------------------------------------------------------------------------
// persistent sequential kernel. 256 wgs x 1024 threads (16 waves), 1 wg/CU.
// Thread map: wave w=tid>>6 (0..15), lane l=tid&63.
//   Gate rows:  o = l>>2 (16 rows/wg), row rA=(o>>2)*1024 + wid*4 + (o&3)
//   Col slices: p = w*4 + (l&3) (64 slices x 32 cols = 2048)
//   Phase C:    o2 = l>>5 (2 y-rows/wg), P = w*32 + (l&31) (512 x 2-col)
__global__ __launch_bounds__(1024)
__attribute__((amdgpu_waves_per_eu(4, 4)))
void lstm_persist(
    const float* __restrict__ Wih1, const float* __restrict__ Whh1,
    const float* __restrict__ Wih2, const float* __restrict__ Whh2,
    const float* __restrict__ Wl,   const float* __restrict__ blp,
    char* __restrict__ wsb, float* __restrict__ out)
{
  float* h1b = (float*)(wsb + WS_H1);
  float* h2b = (float*)(wsb + WS_H2);
  float* yb  = (float*)(wsb + WS_Y);
  const float* biasA_ = (const float*)(wsb + WS_BIASA);
  const float* biasB_ = (const float*)(wsb + WS_BIASB);
  const float* biasE_ = (const float*)(wsb + WS_BIASE);
  const float* rsWC_  = (const float*)(wsb + WS_RSWC);
  const float* feat   = (const float*)(wsb + WS_FEAT);
  const float* WCp    = (const float*)(wsb + WS_WC);

  const int wid = blockIdx.x, tid = threadIdx.x;
  const int w = tid >> 6, l = tid & 63;
  const int o = l >> 2, p4 = l & 3, p = w*4 + p4;
  const int rA = (o >> 2)*1024 + wid*4 + (o & 3);

  // ---- register-resident weight slices (66 floats/thread) ----
  float4 wA[8], wB[8];
  float2 wC;
  #pragma unroll
  for (int i = 0; i < 8; i++){
    int q = p*32 + i*4;
    const float* src;
    if (q < 512)        src = &Wih1[rA*640 + q];
    else if (q < 1536)  src = &Whh1[rA*1024 + (q - 512)];
    else                src = &WCp [rA*512  + (q - 1536)];
    wA[i] = *(const float4*)src;
  }
  #pragma unroll
  for (int i = 0; i < 8; i++){
    int q = p*32 + i*4;
    wB[i] = (q < 1024) ? *(const float4*)&Wih2[rA*1024 + q]
                       : *(const float4*)&Whh2[rA*1024 + (q - 1024)];
  }
  {
    int P = w*32 + (l & 31), o2 = l >> 5;
    wC = *(const float2*)&Wl[(wid*2 + o2)*1024 + P*2];
  }
  float biasAreg = 0.f, biasBreg = 0.f, bEreg = 0.f, rsReg = 0.f, blReg = 0.f;
  float c1 = 0.f, c2 = 0.f;
  if (w == 0 && l < 16){
    int r = (l >> 2)*1024 + wid*4 + (l & 3);
    biasAreg = biasA_[r]; biasBreg = biasB_[r];
    bEreg = biasE_[r];    rsReg = rsWC_[r];
  }
  if (w == 0 && l < 2) blReg = blp[wid*2 + l];

  #pragma unroll
  for (int i = 0; i < 8; i++){ PIN4(wA[i]); }
  #pragma unroll
  for (int i = 0; i < 8; i++){ PIN4(wB[i]); }
  PIN2(wC);
  PIN1(biasAreg); PIN1(biasBreg); PIN1(bEreg); PIN1(rsReg); PIN1(blReg);

  // s_in: 64 slices x 32 cols, padded stride 36 (bank-conflict-free dot reads)
  __shared__ float s_in[64*36];
  __shared__ float s_part[16*20];   // [row o][wave w], stride 20 (f4-aligned)

  for (int t = 0; t < T_STEPS; t++){
    const int rb = t & 1, wbuf = (t + 1) & 1;

    // ================= Phase A: gates1 -> h1 =================
    {
      int q0 = tid*2; float2 v;
      if (q0 < 512){
        v = *(const float2*)&feat[t*512 + q0];
      } else if (q0 < 1536){
        v = AL2(&h1b[rb*1024 + (q0 - 512)]);
      } else {
        v = AL2(&yb[rb*512 + (q0 - 1536)]);
      }
      *(float2*)&s_in[(q0 >> 5)*36 + (q0 & 31)] = v;
    }
    __syncthreads();

    float lse = 0.f;
    if (w == 0 && t > 0){
      // redundant per-wg logsumexp over the 512 y values (cols 1536..2047)
      int base = (48 + (l >> 2))*36 + (l & 3)*8;
      float4 a  = *(float4*)&s_in[base];
      float4 bq = *(float4*)&s_in[base + 4];
      float m0 = fmaxf(fmaxf(fmaxf(a.x,a.y), fmaxf(a.z,a.w)),
                       fmaxf(fmaxf(bq.x,bq.y), fmaxf(bq.z,bq.w)));
      for (int mk = 32; mk; mk >>= 1) m0 = fmaxf(m0, __shfl_xor(m0, mk));
      float s = expf(a.x-m0)+expf(a.y-m0)+expf(a.z-m0)+expf(a.w-m0)
              + expf(bq.x-m0)+expf(bq.y-m0)+expf(bq.z-m0)+expf(bq.w-m0);
      for (int mk = 32; mk; mk >>= 1) s += __shfl_xor(s, mk);
      lse = m0 + logf(s);
      if (wid == 0){  // wg0 emits output row t-1 = y - lse
        float4 o1 = make_float4(a.x-lse, a.y-lse, a.z-lse, a.w-lse);
        float4 o2 = make_float4(bq.x-lse, bq.y-lse, bq.z-lse, bq.w-lse);
        *(float4*)&out[(t-1)*512 + l*8]     = o1;
        *(float4*)&out[(t-1)*512 + l*8 + 4] = o2;
      }
    }

    float acc = 0.f;
    #pragma unroll
    for (int i = 0; i < 8; i++){
      float4 xv = *(float4*)&s_in[p*36 + i*4];
      acc += wA[i].x*xv.x; acc += wA[i].y*xv.y;
      acc += wA[i].z*xv.z; acc += wA[i].w*xv.w;
    }
    acc += __shfl_xor(acc, 1); acc += __shfl_xor(acc, 2);
    if (p4 == 0) s_part[o*20 + w] = acc;
    __syncthreads();
    if (w == 0 && l < 16){
      float4 pa = *(float4*)&s_part[l*20];
      float4 pb = *(float4*)&s_part[l*20 + 4];
      float4 pc = *(float4*)&s_part[l*20 + 8];
      float4 pd = *(float4*)&s_part[l*20 + 12];
      float sum = pa.x+pa.y+pa.z+pa.w + pb.x+pb.y+pb.z+pb.w
                + pc.x+pc.y+pc.z+pc.w + pd.x+pd.y+pd.z+pd.w + biasAreg;
      if (t > 0) sum += bEreg - rsReg*lse;
      float gi = __shfl(sum, (l & 3));
      float gf = __shfl(sum, 4 + (l & 3));
      float gg = __shfl(sum, 8 + (l & 3));
      float go = __shfl(sum, 12 + (l & 3));
      if (l < 4){
        float cn = sigm(gf)*c1 + sigm(gi)*tanhf(gg);
        c1 = cn;
        float hn = sigm(go)*tanhf(cn);
        AS(&h1b[wbuf*1024 + wid*4 + l], hn);
      }
    }
    gbarrier(wsb, wid, t*3 + 0);

    // ================= Phase B: gates2 -> h2 =================
    {
      int q0 = tid*2; float2 v;
      v = (q0 < 1024) ? AL2(&h1b[wbuf*1024 + q0])
                      : AL2(&h2b[rb*1024 + (q0 - 1024)]);
      *(float2*)&s_in[(q0 >> 5)*36 + (q0 & 31)] = v;
    }
    __syncthreads();
    float accB = 0.f;
    #pragma unroll
    for (int i = 0; i < 8; i++){
      float4 xv = *(float4*)&s_in[p*36 + i*4];
      accB += wB[i].x*xv.x; accB += wB[i].y*xv.y;
      accB += wB[i].z*xv.z; accB += wB[i].w*xv.w;
    }
    accB += __shfl_xor(accB, 1); accB += __shfl_xor(accB, 2);
    if (p4 == 0) s_part[o*20 + w] = accB;
    __syncthreads();
    if (w == 0 && l < 16){
      float4 pa = *(float4*)&s_part[l*20];
      float4 pb = *(float4*)&s_part[l*20 + 4];
      float4 pc = *(float4*)&s_part[l*20 + 8];
      float4 pd = *(float4*)&s_part[l*20 + 12];
      float sum = pa.x+pa.y+pa.z+pa.w + pb.x+pb.y+pb.z+pb.w
                + pc.x+pc.y+pc.z+pc.w + pd.x+pd.y+pd.z+pd.w + biasBreg;
      float gi = __shfl(sum, (l & 3));
      float gf = __shfl(sum, 4 + (l & 3));
      float gg = __shfl(sum, 8 + (l & 3));
      float go = __shfl(sum, 12 + (l & 3));
      if (l < 4){
        float cn = sigm(gf)*c2 + sigm(gi)*tanhf(gg);
        c2 = cn;
        float hn = sigm(go)*tanhf(cn);
        AS(&h2b[wbuf*1024 + wid*4 + l], hn);
      }
    }
    gbarrier(wsb, wid, t*3 + 1);

    // ================= Phase C: y = Wl@h2 + bl =================
    if (tid < 512){
      int q0 = tid*2;
      float2 v = AL2(&h2b[wbuf*1024 + q0]);
      *(float2*)&s_in[(q0 >> 5)*36 + (q0 & 31)] = v;
    }
    __syncthreads();
    {
      int P = w*32 + (l & 31), o2 = l >> 5;
      float2 xv = *(float2*)&s_in[(P >> 4)*36 + ((P*2) & 31)];
      float a2 = wC.x*xv.x + wC.y*xv.y;
      for (int mk = 16; mk; mk >>= 1) a2 += __shfl_xor(a2, mk);
      if ((l & 31) == 0) s_part[o2*20 + w] = a2;
    }
    __syncthreads();
    if (w == 0 && l < 2){
      float4 pa = *(float4*)&s_part[l*20];
      float4 pb = *(float4*)&s_part[l*20 + 4];
      float4 pc = *(float4*)&s_part[l*20 + 8];
      float4 pd = *(float4*)&s_part[l*20 + 12];
      float yv = pa.x+pa.y+pa.z+pa.w + pb.x+pb.y+pb.z+pb.w
               + pc.x+pc.y+pc.z+pc.w + pd.x+pd.y+pd.z+pd.w + blReg;
      AS(&yb[wbuf*512 + wid*2 + l], yv);
    }
    gbarrier(wsb, wid, t*3 + 2);
  }

  // ---- tail: emit output row T-1 (final y buffer index = (T)&1 = 0) ----
  if (wid == 0 && w == 0){
    int idx = l*8;
    float yv[8];
    #pragma unroll
    for (int i = 0; i < 8; i++) yv[i] = AL(&yb[idx + i]);
    float m0 = yv[0];
    #pragma unroll
    for (int i = 1; i < 8; i++) m0 = fmaxf(m0, yv[i]);
    for (int mk = 32; mk; mk >>= 1) m0 = fmaxf(m0, __shfl_xor(m0, mk));
    float s = 0.f;
    #pragma unroll
    for (int i = 0; i < 8; i++) s += expf(yv[i] - m0);
    for (int mk = 32; mk; mk >>= 1) s += __shfl_xor(s, mk);
    float lse = m0 + logf(s);
    #pragma unroll
    for (int i = 0; i < 8; i++) out[(T_STEPS-1)*512 + idx + i] = yv[i] - lse;
  }
}

// ---------------------------------------------------------------------------
extern "C" void kernel_launch(void* const* d_in, const int* in_sizes, int n_in,
                              void* d_out, int out_size, void* d_ws, size_t ws_size,
                              hipStream_t stream)
{
  const float* x    = (const float*)d_in[0];
  const float* Ws   = (const float*)d_in[1];
  const float* bs   = (const float*)d_in[2];
  const float* Wih1 = (const float*)d_in[3];
  const float* Whh1 = (const float*)d_in[4];
  const float* bih1 = (const float*)d_in[5];
  const float* bhh1 = (const float*)d_in[6];
  const float* Wih2 = (const float*)d_in[7];
  const float* Whh2 = (const float*)d_in[8];
  const float* bih2 = (const float*)d_in[9];
  const float* bhh2 = (const float*)d_in[10];
  const float* Wl   = (const float*)d_in[11];
  const float* bl   = (const float*)d_in[12];
  const float* Wm   = (const float*)d_in[13];
  const float* bm   = (const float*)d_in[14];
  char* wsb  = (char*)d_ws;
  float* out = (float*)d_out;

  // zero barrier structures + recurrent state (fresh every call / replay)
  hipMemsetAsync(wsb, 0, WS_ZERO_BYTES, stream);

  feat_kernel<<<256, 512, 0, stream>>>(x, Ws, bs, (float*)(wsb + WS_FEAT));
  wc_kernel  <<<256, 512, 0, stream>>>(Wih1, Wm, (float*)(wsb + WS_WC));
  bias_kernel<<<16, 256, 0, stream>>>(bih1, bhh1, bih2, bhh2, Wih1, bm,
                                      (const float*)(wsb + WS_WC),
                                      (float*)(wsb + WS_BIASA), (float*)(wsb + WS_BIASB),
                                      (float*)(wsb + WS_BIASE), (float*)(wsb + WS_RSWC));
  lstm_persist<<<256, 1024, 0, stream>>>(Wih1, Whh1, Wih2, Whh2, Wl, bl, wsb, out);
}